// Round 1
// 1184.752 us; speedup vs baseline: 1.1214x; 1.1214x over previous
//
#include <hip/hip_runtime.h>
#include <math.h>

#define B_    2
#define S_    2048
#define M_TOT 4096
#define DIM_  2048
#define NH_   16
#define QL_   1536
#define KVL_  512
#define QKN_  128
#define QKR_  64
#define VH_   128
#define QKH_  192
#define QSTR  3072      // NH_*QKH_
#define QP_STR 584      // padded LDS row stride for resident Q (576+8)

typedef short s16x8 __attribute__((ext_vector_type(8)));
typedef float f32x4 __attribute__((ext_vector_type(4)));
typedef unsigned short u16;
#define AS1 __attribute__((address_space(1)))
#define AS3 __attribute__((address_space(3)))

__device__ inline u16 f2bf(float f) {
    unsigned u = __float_as_uint(f);
    unsigned r = u + 0x7FFFu + ((u >> 16) & 1u);   // round-to-nearest-even
    return (u16)(r >> 16);
}
__device__ inline float bf2f(u16 h) { return __uint_as_float(((unsigned)h) << 16); }

__device__ __forceinline__ void ld_lds16(const u16* g, u16* l) {
    __builtin_amdgcn_global_load_lds((const AS1 unsigned*)g, (AS3 unsigned*)l, 16, 0, 0);
}
// Raw barriers with explicit publishes. NEVER __syncthreads() in the hot loop:
// its implicit "s_waitcnt vmcnt(0) lgkmcnt(0); s_barrier" drains the
// global_load_lds queue at phase TOP, serializing every phase on load latency.
__device__ __forceinline__ void bar_vm() {      // publish this wave's DMA loads
    asm volatile("s_waitcnt vmcnt(0)" ::: "memory");
    __builtin_amdgcn_s_barrier();
}
__device__ __forceinline__ void bar_lgkm() {    // publish this wave's ds_writes
    asm volatile("s_waitcnt lgkmcnt(0)" ::: "memory");
    __builtin_amdgcn_s_barrier();
}
__device__ __forceinline__ void bar_all() {
    asm volatile("s_waitcnt vmcnt(0) lgkmcnt(0)" ::: "memory");
    __builtin_amdgcn_s_barrier();
}

// ---------------------------------------------------------------------------
// m97-pattern bf16 MFMA GEMM (known good since round 2).
// ---------------------------------------------------------------------------
__global__ __launch_bounds__(256)
void gemm_bf16(const u16* __restrict__ A, const u16* __restrict__ Bm,
               const float* __restrict__ bias, void* __restrict__ Cv,
               int M, int N, int K, int ldA, int ldB, int ldC,
               long long sAz, long long sBz, long long sCz,
               float alpha, int outF32)
{
    __shared__ u16 As[128 * 32];
    __shared__ u16 Bs[128 * 32];
    const int tid = threadIdx.x;
    const int w = tid >> 6, l = tid & 63;
    const int m0 = blockIdx.y * 128, n0 = blockIdx.x * 128;
    const int z = blockIdx.z;
    const u16* Az = A + (size_t)z * sAz;
    const u16* Bz = Bm + (size_t)z * sBz;

    const int rin = l >> 2;
    const int cel = (l & 3) * 8;
    const int lane15 = l & 15, quad = l >> 4;
    const int wm = w & 1, wn = w >> 1;

    f32x4 acc[4][4] = {};

    for (int k0 = 0; k0 < K; k0 += 32) {
        __syncthreads();
        #pragma unroll
        for (int c = 0; c < 2; ++c) {
            const int chunk = w * 2 + c;
            const int rowA = m0 + chunk * 16 + rin;
            const u16* ga = Az + (size_t)rowA * ldA + k0 + cel;
            u16* la = &As[chunk * 512 + rin * 32 + cel];
            __builtin_amdgcn_global_load_lds((const AS1 unsigned*)ga, (AS3 unsigned*)la, 16, 0, 0);
            int rowB = n0 + chunk * 16 + rin;
            if (rowB > N - 1) rowB = N - 1;
            const u16* gb = Bz + (size_t)rowB * ldB + k0 + cel;
            u16* lb = &Bs[chunk * 512 + rin * 32 + cel];
            __builtin_amdgcn_global_load_lds((const AS1 unsigned*)gb, (AS3 unsigned*)lb, 16, 0, 0);
        }
        __syncthreads();
        s16x8 af[4], bf[4];
        #pragma unroll
        for (int i = 0; i < 4; ++i)
            af[i] = *(const s16x8*)&As[(wm * 64 + i * 16 + lane15) * 32 + quad * 8];
        #pragma unroll
        for (int i = 0; i < 4; ++i)
            bf[i] = *(const s16x8*)&Bs[(wn * 64 + i * 16 + lane15) * 32 + quad * 8];
        #pragma unroll
        for (int mi = 0; mi < 4; ++mi)
            #pragma unroll
            for (int ni = 0; ni < 4; ++ni)
                acc[mi][ni] = __builtin_amdgcn_mfma_f32_16x16x32_bf16(af[mi], bf[ni], acc[mi][ni], 0, 0, 0);
    }

    const int cmb = m0 + wm * 64, cnb = n0 + wn * 64;
    if (outF32) {
        float* C = (float*)Cv + (size_t)z * sCz;
        #pragma unroll
        for (int mi = 0; mi < 4; ++mi)
            #pragma unroll
            for (int ni = 0; ni < 4; ++ni) {
                const int nn = cnb + ni * 16 + lane15;
                if (nn < N) {
                    const float bv = bias ? bias[nn] : 0.f;
                    #pragma unroll
                    for (int r = 0; r < 4; ++r) {
                        const int mm = cmb + mi * 16 + quad * 4 + r;
                        C[(size_t)mm * ldC + nn] = acc[mi][ni][r] * alpha + bv;
                    }
                }
            }
    } else {
        u16* C = (u16*)Cv + (size_t)z * sCz;
        #pragma unroll
        for (int mi = 0; mi < 4; ++mi)
            #pragma unroll
            for (int ni = 0; ni < 4; ++ni) {
                const int nn = cnb + ni * 16 + lane15;
                if (nn < N) {
                    const float bv = bias ? bias[nn] : 0.f;
                    #pragma unroll
                    for (int r = 0; r < 4; ++r) {
                        const int mm = cmb + mi * 16 + quad * 4 + r;
                        C[(size_t)mm * ldC + nn] = f2bf(acc[mi][ni][r] * alpha + bv);
                    }
                }
            }
    }
}

// ---------------------------------------------------------------------------
// Flash v4: latency-bound fix of v3 (v3: MfmaUtil 7%, 17 draining barriers /
// k-tile). Schedule per phase: ISSUE next-chunk global_load_lds -> compute
// current chunk -> s_waitcnt vmcnt(0) -> raw s_barrier. The drain now sits
// AFTER ~1000 cyc of ds_read+MFMA, hiding L2/L3 latency; loads are in flight
// across every barrier. Score chunks 96 dims (6 phases, uniform 3 loads/thr).
// V chunk 0 issued during score phase 5 (drained at barrier C); next k-tile's
// K chunk 0 issued during PV tc=3. Softmax: barrier B + serial tid<64 stage
// replaced by all-thread redundant reduce of per-slice partials (b128
// broadcast reads); per-row m/l state updated by designated lanes after C.
// Barriers/k-tile: 17 -> 11, none latency-exposed.
// Buffer schedule (32KB each): score j reads buf[j&1], stages K(j+1)->buf[~],
// j=5 stages V0->buf0; PV tc reads buf[tc&1], stages V(tc+1)->buf[~],
// tc=3 stages next K0->buf0. Every write is barrier-separated from the
// previous read of that buffer.
// LDS: 74752(Q) + 65536(K/V dbuf) + 17408(P) + 2560(misc) = 160256 B.
// ---------------------------------------------------------------------------
__global__ __launch_bounds__(512)
void mla_flash(u16* __restrict__ Qp, const u16* __restrict__ Kcat,
               const u16* __restrict__ KVT)
{
    __shared__ u16 sQ[64 * QP_STR];          // 74752 B
    __shared__ u16 sKV[2][16384];            // 65536 B (K chunk 24KB / V chunk 32KB)
    __shared__ u16 sP[64 * 136];             // 17408 B
    __shared__ float sRm[64 * 4];            // per-row max partials (4 k-slices)
    __shared__ float sRs[64 * 4];            // per-row sum partials
    __shared__ float sM[64], sL[64];

    const int tid = threadIdx.x;
    const int w = tid >> 6, l = tid & 63;
    const int lane15 = l & 15, quad = l >> 4;
    const int wq = w & 1;                    // q-half (rows wq*32 ..)
    const int wk = w >> 1;                   // score k-slice / PV c-slice
    const int qt = 31 - blockIdx.x;          // heavy tiles first
    const int h = blockIdx.y, b = blockIdx.z;
    const int qs = qt * 64;
    u16* Qrow = Qp + ((size_t)h * M_TOT + b * S_ + qs) * 576;
    const float scale = 0.07216878364870323f;  // 1/sqrt(192)
    const u16* Kb = Kcat + (size_t)b * S_ * 576;
    const u16* Vb = KVT + (size_t)b * 512 * S_;

    const int key = tid >> 2;                // 0..127
    const int seg8 = (tid & 3) * 8;          // 16B segment within 32-dim row
    const int ktiles = (qs + 191) >> 7;

    // K chunk j (dims j*96..+96) -> buf: wave-linear LDS dest (base + lane*16)
    auto stageK = [&](int kt, int j, int buf) {
        #pragma unroll
        for (int kk = 0; kk < 3; ++kk) {
            const u16* g = Kb + (size_t)(kt + key) * 576 + j * 96 + kk * 32 + seg8;
            ld_lds16(g, &sKV[buf][kk * 4096 + key * 32 + seg8]);
        }
    };
    // V t-chunk tc (cols kt+tc*32..+32, all 512 c-rows) -> buf
    auto stageV = [&](int kt, int tc, int buf) {
        #pragma unroll
        for (int jj = 0; jj < 4; ++jj) {
            const int c = jj * 128 + key;
            const u16* g = Vb + (size_t)c * S_ + kt + tc * 32 + seg8;
            ld_lds16(g, &sKV[buf][jj * 4096 + key * 32 + seg8]);
        }
    };

    // ---- prologue: issue K chunk 0 first, hide under Q fill ----
    stageK(0, 0, 0);
    {
        const int r = tid >> 3, c0 = (tid & 7) * 8;
        #pragma unroll
        for (int jj = 0; jj < 9; ++jj) {
            const int c = c0 + jj * 64;
            *(s16x8*)&sQ[r * QP_STR + c] = *(const s16x8*)&Qrow[(size_t)r * 576 + c];
        }
    }
    if (tid < 64) { sM[tid] = -1e30f; sL[tid] = 0.f; }
    bar_all();

    f32x4 Oacc[2][8] = {};                   // rows wq*32+mi*16+..., cols wk*128+ci*16+...
    float mn_[2][4], al_[2][4];              // static-indexed per-row softmax state

    for (int kt0 = 0; kt0 < ktiles; ++kt0) {
        const int kt = kt0 << 7;
        f32x4 Sacc[2][2] = {};

        // ---- score: S(64x128) = Q . K^T, 6 phases of 96 dims ----
        #pragma unroll
        for (int j = 0; j < 6; ++j) {
            const int cur = j & 1;
            if (j < 5) stageK(kt, j + 1, cur ^ 1);
            else       stageV(kt, 0, 0);     // V0 in flight across softmax, drained at C
            __builtin_amdgcn_s_setprio(1);
            #pragma unroll
            for (int kk = 0; kk < 3; ++kk) {
                s16x8 af[2], bf[2];
                #pragma unroll
                for (int mi = 0; mi < 2; ++mi)
                    af[mi] = *(const s16x8*)&sQ[(wq * 32 + mi * 16 + lane15) * QP_STR + j * 96 + kk * 32 + quad * 8];
                #pragma unroll
                for (int ni = 0; ni < 2; ++ni)
                    bf[ni] = *(const s16x8*)&sKV[cur][kk * 4096 + (wk * 32 + ni * 16 + lane15) * 32 + quad * 8];
                #pragma unroll
                for (int mi = 0; mi < 2; ++mi)
                    #pragma unroll
                    for (int ni = 0; ni < 2; ++ni)
                        Sacc[mi][ni] = __builtin_amdgcn_mfma_f32_16x16x32_bf16(af[mi], bf[ni], Sacc[mi][ni], 0, 0, 0);
            }
            __builtin_amdgcn_s_setprio(0);
            if (j < 5) bar_vm();             // publish K(j+1); j=5 needs no barrier
        }

        // ---- softmax part 1: scale + causal mask + per-slice row max ----
        #pragma unroll
        for (int mi = 0; mi < 2; ++mi)
            #pragma unroll
            for (int r = 0; r < 4; ++r) {
                const int rowl = wq * 32 + mi * 16 + quad * 4 + r;
                const int rowg = qs + rowl;
                float mx = -1e30f;
                #pragma unroll
                for (int ni = 0; ni < 2; ++ni) {
                    const int colg = kt + wk * 32 + ni * 16 + lane15;
                    float v = Sacc[mi][ni][r] * scale;
                    v = (colg <= rowg) ? v : -1e30f;
                    Sacc[mi][ni][r] = v;
                    mx = fmaxf(mx, v);
                }
                #pragma unroll
                for (int sh = 1; sh < 16; sh <<= 1) mx = fmaxf(mx, __shfl_xor(mx, sh));
                if (lane15 == 0) sRm[rowl * 4 + wk] = mx;
            }
        bar_lgkm();                          // (A): sRm visible

        // ---- part 2 (all threads, no barrier B): m,alpha redundantly; P;
        //      rescale O; per-slice row sums ----
        #pragma unroll
        for (int mi = 0; mi < 2; ++mi)
            #pragma unroll
            for (int r = 0; r < 4; ++r) {
                const int rowl = wq * 32 + mi * 16 + quad * 4 + r;
                const f32x4 pm = *(const f32x4*)&sRm[rowl * 4];   // broadcast b128
                const float m_old = sM[rowl];
                const float mn = fmaxf(fmaxf(fmaxf(pm[0], pm[1]), fmaxf(pm[2], pm[3])), m_old);
                const float al = __expf(m_old - mn);
                mn_[mi][r] = mn; al_[mi][r] = al;
                float sum = 0.f;
                #pragma unroll
                for (int ni = 0; ni < 2; ++ni) {
                    const float p = __expf(Sacc[mi][ni][r] - mn);
                    sP[rowl * 136 + wk * 32 + ni * 16 + lane15] = f2bf(p);
                    sum += p;
                }
                #pragma unroll
                for (int ci = 0; ci < 8; ++ci) Oacc[mi][ci][r] *= al;
                #pragma unroll
                for (int sh = 1; sh < 16; sh <<= 1) sum += __shfl_xor(sum, sh);
                if (lane15 == 0) sRs[rowl * 4 + wk] = sum;
            }
        bar_all();                           // (C): sP + sRs visible, V0 arrived

        // ---- part 3: designated lanes update per-row m/l (no barrier;
        //      consumers are >=1 barrier away) ----
        if (wk == 0 && lane15 == 0) {
            #pragma unroll
            for (int mi = 0; mi < 2; ++mi)
                #pragma unroll
                for (int r = 0; r < 4; ++r) {
                    const int rowl = wq * 32 + mi * 16 + quad * 4 + r;
                    const f32x4 ps = *(const f32x4*)&sRs[rowl * 4];
                    sL[rowl] = sL[rowl] * al_[mi][r] + (ps[0] + ps[1] + ps[2] + ps[3]);
                    sM[rowl] = mn_[mi][r];
                }
        }

        // ---- PV: O(64x512) += P(64x128) . KV(128x512), 4 t-chunks of 32 ----
        #pragma unroll
        for (int tc = 0; tc < 4; ++tc) {
            const int cur = tc & 1;
            if (tc < 3)                 stageV(kt, tc + 1, cur ^ 1);
            else if (kt0 + 1 < ktiles)  stageK(kt + 128, 0, 0);   // next tile's K0
            s16x8 pf[2], vf[8];
            #pragma unroll
            for (int mi = 0; mi < 2; ++mi)
                pf[mi] = *(const s16x8*)&sP[(wq * 32 + mi * 16 + lane15) * 136 + tc * 32 + quad * 8];
            #pragma unroll
            for (int ci = 0; ci < 8; ++ci)
                vf[ci] = *(const s16x8*)&sKV[cur][(wk * 128 + ci * 16 + lane15) * 32 + quad * 8];
            __builtin_amdgcn_s_setprio(1);
            #pragma unroll
            for (int mi = 0; mi < 2; ++mi)
                #pragma unroll
                for (int ci = 0; ci < 8; ++ci)
                    Oacc[mi][ci] = __builtin_amdgcn_mfma_f32_16x16x32_bf16(pf[mi], vf[ci], Oacc[mi][ci], 0, 0, 0);
            __builtin_amdgcn_s_setprio(0);
            bar_vm();                        // publish V(tc+1) / next K0
        }
    }

    // ---- epilogue: O/l -> bf16, overwrite Qpack[..., 0:512] ----
    bar_lgkm();
    #pragma unroll
    for (int mi = 0; mi < 2; ++mi)
        #pragma unroll
        for (int r = 0; r < 4; ++r) {
            const int rowl = wq * 32 + mi * 16 + quad * 4 + r;
            const float inv = 1.f / sL[rowl];
            #pragma unroll
            for (int ci = 0; ci < 8; ++ci)
                Qrow[(size_t)rowl * 576 + wk * 128 + ci * 16 + lane15] =
                    f2bf(Oacc[mi][ci][r] * inv);
        }
}

// ---------------------------------------------------------------------------
__global__ __launch_bounds__(256)
void cast_f32_bf16(const float* __restrict__ src, u16* __restrict__ dst, int n)
{
    for (int i = blockIdx.x * 256 + threadIdx.x; i < n; i += gridDim.x * 256)
        dst[i] = f2bf(src[i]);
}

__global__ __launch_bounds__(256)
void prep_wbnT(const float* __restrict__ wkvb, u16* __restrict__ dst)
{
    int i = blockIdx.x * 256 + threadIdx.x;
    int h = i >> 16, rem = i & 65535, c = rem >> 7, d = rem & 127;
    dst[i] = f2bf(wkvb[(size_t)(h * 256 + d) * 512 + c]);
}

__global__ __launch_bounds__(256)
void prep_wbv(const float* __restrict__ wkvb, u16* __restrict__ dst)
{
    int i = blockIdx.x * 256 + threadIdx.x;
    int h = i >> 16, rem = i & 65535;
    dst[i] = f2bf(wkvb[(size_t)h * 131072 + 65536 + rem]);
}

__global__ __launch_bounds__(256)
void rmsnorm_bf16(u16* __restrict__ X, const float* __restrict__ w, int D)
{
    const int m = blockIdx.x;
    u16* x = X + (size_t)m * D;
    float ss = 0.f;
    for (int k = threadIdx.x; k < D; k += 256) { float v = bf2f(x[k]); ss += v * v; }
    __shared__ float red[256];
    red[threadIdx.x] = ss; __syncthreads();
    for (int s = 128; s > 0; s >>= 1) {
        if (threadIdx.x < s) red[threadIdx.x] += red[threadIdx.x + s];
        __syncthreads();
    }
    const float sc = rsqrtf(red[0] / (float)D + 1e-6f);
    for (int k = threadIdx.x; k < D; k += 256) x[k] = f2bf(bf2f(x[k]) * sc * w[k]);
}

// q (bf16, rows QSTR) -> rotate q_pe, write to Qpack[h][m][512:576]
__global__ __launch_bounds__(256)
void rope_q(const u16* __restrict__ q, const float* __restrict__ freqs, u16* __restrict__ Qp)
{
    const int idx = blockIdx.x * 256 + threadIdx.x;
    const int i = idx & 31, h = (idx >> 5) & 15, m = idx >> 9;
    const int s = m & (S_ - 1);
    const float c = freqs[(s * 32 + i) * 2], sn = freqs[(s * 32 + i) * 2 + 1];
    const u16* src = q + (size_t)m * QSTR + h * QKH_ + QKN_ + 2 * i;
    const float x0 = bf2f(src[0]), x1 = bf2f(src[1]);
    u16* dst = Qp + ((size_t)h * M_TOT + m) * 576 + 512 + 2 * i;
    dst[0] = f2bf(x0 * c - x1 * sn);
    dst[1] = f2bf(x1 * c + x0 * sn);
}

__global__ __launch_bounds__(256)
void kv_norm_rope(const u16* __restrict__ kva, const float* __restrict__ w,
                  const float* __restrict__ freqs, u16* __restrict__ Kcat)
{
    const int m = blockIdx.x, s = m & (S_ - 1);
    const u16* x = kva + (size_t)m * 576;
    float ss = 0.f;
    for (int k = threadIdx.x; k < 512; k += 256) { float v = bf2f(x[k]); ss += v * v; }
    __shared__ float red[256];
    red[threadIdx.x] = ss; __syncthreads();
    for (int st = 128; st > 0; st >>= 1) {
        if (threadIdx.x < st) red[threadIdx.x] += red[threadIdx.x + st];
        __syncthreads();
    }
    const float sc = rsqrtf(red[0] / 512.f + 1e-6f);
    for (int k = threadIdx.x; k < 512; k += 256)
        Kcat[(size_t)m * 576 + k] = f2bf(bf2f(x[k]) * sc * w[k]);
    if (threadIdx.x < 32) {
        const int i = threadIdx.x;
        const float c = freqs[(s * 32 + i) * 2], sn = freqs[(s * 32 + i) * 2 + 1];
        const float x0 = bf2f(x[512 + 2 * i]), x1 = bf2f(x[512 + 2 * i + 1]);
        Kcat[(size_t)m * 576 + 512 + 2 * i]     = f2bf(x0 * c - x1 * sn);
        Kcat[(size_t)m * 576 + 512 + 2 * i + 1] = f2bf(x1 * c + x0 * sn);
    }
}

__global__ __launch_bounds__(256)
void transpose_kv(const u16* __restrict__ Kcat, u16* __restrict__ KVT)
{
    __shared__ u16 t[64][65];
    const int s0 = blockIdx.x * 64, c0 = blockIdx.y * 64, b = blockIdx.z;
    #pragma unroll
    for (int i = 0; i < 16; ++i) {
        int id = i * 256 + threadIdx.x, r = id >> 6, c = id & 63;
        t[r][c] = Kcat[(size_t)(b * S_ + s0 + r) * 576 + c0 + c];
    }
    __syncthreads();
    #pragma unroll
    for (int i = 0; i < 16; ++i) {
        int id = i * 256 + threadIdx.x, r = id >> 6, c = id & 63;
        KVT[(size_t)(b * 512 + c0 + r) * S_ + s0 + c] = t[c][r];
    }
}

// ---------------------------------------------------------------------------
extern "C" void kernel_launch(void* const* d_in, const int* in_sizes, int n_in,
                              void* d_out, int out_size, void* d_ws, size_t ws_size,
                              hipStream_t stream)
{
    (void)in_sizes; (void)n_in; (void)out_size; (void)ws_size;
    const float* x         = (const float*)d_in[0];
    const float* freqs     = (const float*)d_in[1];
    const float* wq_a_w    = (const float*)d_in[4];
    const float* wq_a_b    = (const float*)d_in[5];
    const float* q_norm_w  = (const float*)d_in[6];
    const float* wq_b_w    = (const float*)d_in[7];
    const float* wq_b_b    = (const float*)d_in[8];
    const float* wkv_a_w   = (const float*)d_in[9];
    const float* wkv_a_b   = (const float*)d_in[10];
    const float* kv_norm_w = (const float*)d_in[11];
    const float* wkv_b_w   = (const float*)d_in[12];
    const float* wo_w      = (const float*)d_in[13];
    const float* wo_b      = (const float*)d_in[14];
    float* out = (float*)d_out;

    char* W = (char*)d_ws;
    u16* x_bf  = (u16*)(W + 0);
    u16* wqa   = (u16*)(W + 16777216);
    u16* wqb   = (u16*)(W + 23068672);
    u16* wkva  = (u16*)(W + 32505856);
    u16* wobf  = (u16*)(W + 34865152);
    u16* wbnT  = (u16*)(W + 43253760);
    u16* wbv   = (u16*)(W + 45350912);
    u16* q_a   = (u16*)(W + 47448064);
    u16* q     = (u16*)(W + 60030976);
    u16* kv_a  = (u16*)(W + 85196800);
    u16* Kcat  = (u16*)(W + 89915392);
    u16* KVT   = (u16*)(W + 94633984);
    u16* Qp    = (u16*)(W + 98828288);   // Qpack[h][4096][576]: q_abs|q_pe -> attn out
    u16* outh  = (u16*)(W + 174325760);

    const dim3 blk(256);

    // --- dtype prep ---
    cast_f32_bf16<<<2048, blk, 0, stream>>>(x, x_bf, M_TOT * DIM_);
    cast_f32_bf16<<<2048, blk, 0, stream>>>(wq_a_w, wqa, QL_ * DIM_);
    cast_f32_bf16<<<2048, blk, 0, stream>>>(wq_b_w, wqb, QSTR * QL_);
    cast_f32_bf16<<<2048, blk, 0, stream>>>(wkv_a_w, wkva, 576 * DIM_);
    cast_f32_bf16<<<2048, blk, 0, stream>>>(wo_w, wobf, DIM_ * DIM_);
    prep_wbnT<<<4096, blk, 0, stream>>>(wkv_b_w, wbnT);
    prep_wbv<<<4096, blk, 0, stream>>>(wkv_b_w, wbv);

    // --- q path ---
    gemm_bf16<<<dim3(12, 32, 1), blk, 0, stream>>>(x_bf, wqa, wq_a_b, q_a,
        M_TOT, QL_, DIM_, DIM_, DIM_, QL_, 0, 0, 0, 1.f, 0);
    rmsnorm_bf16<<<M_TOT, blk, 0, stream>>>(q_a, q_norm_w, QL_);
    gemm_bf16<<<dim3(24, 32, 1), blk, 0, stream>>>(q_a, wqb, wq_b_b, q,
        M_TOT, QSTR, QL_, QL_, QL_, QSTR, 0, 0, 0, 1.f, 0);
    rope_q<<<(M_TOT * NH_ * 32) / 256, blk, 0, stream>>>(q, freqs, Qp);

    // --- kv path ---
    gemm_bf16<<<dim3(5, 32, 1), blk, 0, stream>>>(x_bf, wkva, wkv_a_b, kv_a,
        M_TOT, 576, DIM_, DIM_, DIM_, 576, 0, 0, 0, 1.f, 0);
    kv_norm_rope<<<M_TOT, blk, 0, stream>>>(kv_a, kv_norm_w, freqs, Kcat);
    transpose_kv<<<dim3(32, 8, 2), blk, 0, stream>>>(Kcat, KVT);

    // --- q absorb: Qpack[h][m][0:512] = q_nope @ wkv_b[h,:128,:] ---
    gemm_bf16<<<dim3(4, 32, 16), blk, 0, stream>>>(q, wbnT, nullptr, Qp,
        M_TOT, 512, 128, QSTR, 128, 576, QKH_, 65536, (long long)M_TOT * 576, 1.f, 0);

    // --- fused flash attention v4 ---
    mla_flash<<<dim3(32, 16, 2), dim3(512), 0, stream>>>(Qp, Kcat, KVT);

    // --- V projection: outh[m][h*128+d] = O[h][m][:] . wbv[h][d][:] ---
    gemm_bf16<<<dim3(1, 32, 16), blk, 0, stream>>>(Qp, wbv, nullptr, outh,
        M_TOT, VH_, 512, 576, 512, DIM_, (long long)M_TOT * 576, 65536, VH_, 1.f, 0);

    // --- output projection (fp32 out) ---
    gemm_bf16<<<dim3(16, 32, 1), blk, 0, stream>>>(outh, wobf, wo_b, out,
        M_TOT, DIM_, DIM_, DIM_, DIM_, DIM_, 0, 0, 0, 1.f, 1);
}

// Round 2
// 851.090 us; speedup vs baseline: 1.5611x; 1.3920x over previous
//
#include <hip/hip_runtime.h>
#include <math.h>

#define B_    2
#define S_    2048
#define M_TOT 4096
#define DIM_  2048
#define NH_   16
#define QL_   1536
#define KVL_  512
#define QKN_  128
#define QKR_  64
#define VH_   128
#define QKH_  192
#define QSTR  3072      // NH_*QKH_
#define QP_STR 584      // padded LDS row stride for resident Q (576+8)

typedef short s16x8 __attribute__((ext_vector_type(8)));
typedef float f32x4 __attribute__((ext_vector_type(4)));
typedef unsigned short u16;
#define AS1 __attribute__((address_space(1)))
#define AS3 __attribute__((address_space(3)))

__device__ inline u16 f2bf(float f) {
    unsigned u = __float_as_uint(f);
    unsigned r = u + 0x7FFFu + ((u >> 16) & 1u);   // round-to-nearest-even
    return (u16)(r >> 16);
}
__device__ inline float bf2f(u16 h) { return __uint_as_float(((unsigned)h) << 16); }

__device__ __forceinline__ void ld_lds16(const u16* g, u16* l) {
    __builtin_amdgcn_global_load_lds((const AS1 unsigned*)g, (AS3 unsigned*)l, 16, 0, 0);
}
// Raw barriers with explicit publishes. NEVER __syncthreads() in the hot loop:
// its implicit "s_waitcnt vmcnt(0) lgkmcnt(0); s_barrier" drains the
// global_load_lds queue at phase TOP, serializing every phase on load latency.
__device__ __forceinline__ void bar_vm() {      // publish this wave's DMA loads
    asm volatile("s_waitcnt vmcnt(0)" ::: "memory");
    __builtin_amdgcn_s_barrier();
}
__device__ __forceinline__ void bar_lgkm() {    // publish this wave's ds_writes
    asm volatile("s_waitcnt lgkmcnt(0)" ::: "memory");
    __builtin_amdgcn_s_barrier();
}
__device__ __forceinline__ void bar_all() {
    asm volatile("s_waitcnt vmcnt(0) lgkmcnt(0)" ::: "memory");
    __builtin_amdgcn_s_barrier();
}

// ---------------------------------------------------------------------------
// m97-pattern bf16 MFMA GEMM (known good since round 2).
// ---------------------------------------------------------------------------
__global__ __launch_bounds__(256)
void gemm_bf16(const u16* __restrict__ A, const u16* __restrict__ Bm,
               const float* __restrict__ bias, void* __restrict__ Cv,
               int M, int N, int K, int ldA, int ldB, int ldC,
               long long sAz, long long sBz, long long sCz,
               float alpha, int outF32)
{
    __shared__ u16 As[128 * 32];
    __shared__ u16 Bs[128 * 32];
    const int tid = threadIdx.x;
    const int w = tid >> 6, l = tid & 63;
    const int m0 = blockIdx.y * 128, n0 = blockIdx.x * 128;
    const int z = blockIdx.z;
    const u16* Az = A + (size_t)z * sAz;
    const u16* Bz = Bm + (size_t)z * sBz;

    const int rin = l >> 2;
    const int cel = (l & 3) * 8;
    const int lane15 = l & 15, quad = l >> 4;
    const int wm = w & 1, wn = w >> 1;

    f32x4 acc[4][4] = {};

    for (int k0 = 0; k0 < K; k0 += 32) {
        __syncthreads();
        #pragma unroll
        for (int c = 0; c < 2; ++c) {
            const int chunk = w * 2 + c;
            const int rowA = m0 + chunk * 16 + rin;
            const u16* ga = Az + (size_t)rowA * ldA + k0 + cel;
            u16* la = &As[chunk * 512 + rin * 32 + cel];
            __builtin_amdgcn_global_load_lds((const AS1 unsigned*)ga, (AS3 unsigned*)la, 16, 0, 0);
            int rowB = n0 + chunk * 16 + rin;
            if (rowB > N - 1) rowB = N - 1;
            const u16* gb = Bz + (size_t)rowB * ldB + k0 + cel;
            u16* lb = &Bs[chunk * 512 + rin * 32 + cel];
            __builtin_amdgcn_global_load_lds((const AS1 unsigned*)gb, (AS3 unsigned*)lb, 16, 0, 0);
        }
        __syncthreads();
        s16x8 af[4], bf[4];
        #pragma unroll
        for (int i = 0; i < 4; ++i)
            af[i] = *(const s16x8*)&As[(wm * 64 + i * 16 + lane15) * 32 + quad * 8];
        #pragma unroll
        for (int i = 0; i < 4; ++i)
            bf[i] = *(const s16x8*)&Bs[(wn * 64 + i * 16 + lane15) * 32 + quad * 8];
        #pragma unroll
        for (int mi = 0; mi < 4; ++mi)
            #pragma unroll
            for (int ni = 0; ni < 4; ++ni)
                acc[mi][ni] = __builtin_amdgcn_mfma_f32_16x16x32_bf16(af[mi], bf[ni], acc[mi][ni], 0, 0, 0);
    }

    const int cmb = m0 + wm * 64, cnb = n0 + wn * 64;
    if (outF32) {
        float* C = (float*)Cv + (size_t)z * sCz;
        #pragma unroll
        for (int mi = 0; mi < 4; ++mi)
            #pragma unroll
            for (int ni = 0; ni < 4; ++ni) {
                const int nn = cnb + ni * 16 + lane15;
                if (nn < N) {
                    const float bv = bias ? bias[nn] : 0.f;
                    #pragma unroll
                    for (int r = 0; r < 4; ++r) {
                        const int mm = cmb + mi * 16 + quad * 4 + r;
                        C[(size_t)mm * ldC + nn] = acc[mi][ni][r] * alpha + bv;
                    }
                }
            }
    } else {
        u16* C = (u16*)Cv + (size_t)z * sCz;
        #pragma unroll
        for (int mi = 0; mi < 4; ++mi)
            #pragma unroll
            for (int ni = 0; ni < 4; ++ni) {
                const int nn = cnb + ni * 16 + lane15;
                if (nn < N) {
                    const float bv = bias ? bias[nn] : 0.f;
                    #pragma unroll
                    for (int r = 0; r < 4; ++r) {
                        const int mm = cmb + mi * 16 + quad * 4 + r;
                        C[(size_t)mm * ldC + nn] = f2bf(acc[mi][ni][r] * alpha + bv);
                    }
                }
            }
    }
}

// ---------------------------------------------------------------------------
// Flash v5 = v4 schedule + two locality fixes:
// (1) XCD-aware block swizzle (T1): grid flattened to 1024; xcd = flat&7;
//     XCDs 0-3 serve b=0, XCDs 4-7 serve b=1 -> per-XCD L2 KV working set
//     4.3MB (~L2-fit) instead of 8.6MB (thrash->L3, exposed latency at each
//     phase's vmcnt wait).
// (2) LDS XOR swizzle for K/V (T2 via m173 source-permute, rule #21):
//     sKV rows are 64B, so lanes 0-15 at row-stride 64B were an 8-way bank
//     conflict on every bf/vf ds_read_b128 (68 of 112 reads/k-tile,
//     SQ_LDS_BANK_CONFLICT 3.1e7). Keep global_load_lds dest LINEAR; permute
//     the 16B segment in the GLOBAL source by P=(key>>1)&3 (store side
//     sx8 = ((tid&3)^((tid>>3)&3))*8); read with the same XOR (read side
//     qx8 = (quad^((lane15>>1)&3))*8 -- P collapses to a per-thread constant
//     for every fragment because ni*16/ci*16/wk offsets are 0 mod 4 after
//     >>1). XOR is an involution: slot(key,s) holds segment s^P(key); read
//     of (key,quad) fetches slot quad^P(key) -> segment quad. 8-way -> 2-way
//     (free per m136).
// v4 schedule recap: per phase ISSUE next-chunk loads -> MFMA -> vmcnt(0) ->
// s_barrier; 6 score phases of 96 dims; V0 staged during phase 5, drained at
// C; next tile's K0 staged during PV tc=3; 11 barriers/k-tile, none
// latency-exposed.
// LDS: 74752(Q) + 65536(K/V dbuf) + 17408(P) + 2560(misc) = 160256 B.
// ---------------------------------------------------------------------------
__global__ __launch_bounds__(512)
void mla_flash(u16* __restrict__ Qp, const u16* __restrict__ Kcat,
               const u16* __restrict__ KVT)
{
    __shared__ u16 sQ[64 * QP_STR];          // 74752 B
    __shared__ u16 sKV[2][16384];            // 65536 B (K chunk 24KB / V chunk 32KB)
    __shared__ u16 sP[64 * 136];             // 17408 B
    __shared__ float sRm[64 * 4];            // per-row max partials (4 k-slices)
    __shared__ float sRs[64 * 4];            // per-row sum partials
    __shared__ float sM[64], sL[64];

    const int tid = threadIdx.x;
    const int w = tid >> 6, l = tid & 63;
    const int lane15 = l & 15, quad = l >> 4;
    const int wq = w & 1;                    // q-half (rows wq*32 ..)
    const int wk = w >> 1;                   // score k-slice / PV c-slice

    // --- XCD-aware decode: xcd = flat&7 (round-robin dispatch). b pinned per
    // XCD half; h,qt tiled within. Bijective over 1024 blocks. qt descending
    // in dispatch order (heavy tiles first).
    const int flat = blockIdx.x;
    const int xcd  = flat & 7;
    const int slot = flat >> 3;              // 0..127
    const int b    = xcd >> 2;
    const int h    = (xcd & 3) * 4 + (slot & 3);
    const int qt   = 31 - (slot >> 2);

    const int qs = qt * 64;
    u16* Qrow = Qp + ((size_t)h * M_TOT + b * S_ + qs) * 576;
    const float scale = 0.07216878364870323f;  // 1/sqrt(192)
    const u16* Kb = Kcat + (size_t)b * S_ * 576;
    const u16* Vb = KVT + (size_t)b * 512 * S_;

    const int key = tid >> 2;                // 0..127
    const int seg8 = (tid & 3) * 8;          // linear LDS dest segment
    const int sx8  = (((tid & 3) ^ ((tid >> 3) & 3)) * 8);   // permuted SRC segment
    const int qx8  = ((quad ^ ((lane15 >> 1) & 3)) * 8);     // permuted READ segment
    const int ktiles = (qs + 191) >> 7;

    // K chunk j (dims j*96..+96) -> buf: linear LDS dest, XOR-permuted source
    auto stageK = [&](int kt, int j, int buf) {
        #pragma unroll
        for (int kk = 0; kk < 3; ++kk) {
            const u16* g = Kb + (size_t)(kt + key) * 576 + j * 96 + kk * 32 + sx8;
            ld_lds16(g, &sKV[buf][kk * 4096 + key * 32 + seg8]);
        }
    };
    // V t-chunk tc (cols kt+tc*32..+32, all 512 c-rows) -> buf
    auto stageV = [&](int kt, int tc, int buf) {
        #pragma unroll
        for (int jj = 0; jj < 4; ++jj) {
            const int c = jj * 128 + key;
            const u16* g = Vb + (size_t)c * S_ + kt + tc * 32 + sx8;
            ld_lds16(g, &sKV[buf][jj * 4096 + key * 32 + seg8]);
        }
    };

    // ---- prologue: issue K chunk 0 first, hide under Q fill ----
    stageK(0, 0, 0);
    {
        const int r = tid >> 3, c0 = (tid & 7) * 8;
        #pragma unroll
        for (int jj = 0; jj < 9; ++jj) {
            const int c = c0 + jj * 64;
            *(s16x8*)&sQ[r * QP_STR + c] = *(const s16x8*)&Qrow[(size_t)r * 576 + c];
        }
    }
    if (tid < 64) { sM[tid] = -1e30f; sL[tid] = 0.f; }
    bar_all();

    f32x4 Oacc[2][8] = {};                   // rows wq*32+mi*16+..., cols wk*128+ci*16+...
    float mn_[2][4], al_[2][4];              // static-indexed per-row softmax state

    for (int kt0 = 0; kt0 < ktiles; ++kt0) {
        const int kt = kt0 << 7;
        f32x4 Sacc[2][2] = {};

        // ---- score: S(64x128) = Q . K^T, 6 phases of 96 dims ----
        #pragma unroll
        for (int j = 0; j < 6; ++j) {
            const int cur = j & 1;
            if (j < 5) stageK(kt, j + 1, cur ^ 1);
            else       stageV(kt, 0, 0);     // V0 in flight across softmax, drained at C
            __builtin_amdgcn_s_setprio(1);
            #pragma unroll
            for (int kk = 0; kk < 3; ++kk) {
                s16x8 af[2], bf[2];
                #pragma unroll
                for (int mi = 0; mi < 2; ++mi)
                    af[mi] = *(const s16x8*)&sQ[(wq * 32 + mi * 16 + lane15) * QP_STR + j * 96 + kk * 32 + quad * 8];
                #pragma unroll
                for (int ni = 0; ni < 2; ++ni)
                    bf[ni] = *(const s16x8*)&sKV[cur][kk * 4096 + (wk * 32 + ni * 16 + lane15) * 32 + qx8];
                #pragma unroll
                for (int mi = 0; mi < 2; ++mi)
                    #pragma unroll
                    for (int ni = 0; ni < 2; ++ni)
                        Sacc[mi][ni] = __builtin_amdgcn_mfma_f32_16x16x32_bf16(af[mi], bf[ni], Sacc[mi][ni], 0, 0, 0);
            }
            __builtin_amdgcn_s_setprio(0);
            if (j < 5) bar_vm();             // publish K(j+1); j=5 needs no barrier
        }

        // ---- softmax part 1: scale + causal mask + per-slice row max ----
        #pragma unroll
        for (int mi = 0; mi < 2; ++mi)
            #pragma unroll
            for (int r = 0; r < 4; ++r) {
                const int rowl = wq * 32 + mi * 16 + quad * 4 + r;
                const int rowg = qs + rowl;
                float mx = -1e30f;
                #pragma unroll
                for (int ni = 0; ni < 2; ++ni) {
                    const int colg = kt + wk * 32 + ni * 16 + lane15;
                    float v = Sacc[mi][ni][r] * scale;
                    v = (colg <= rowg) ? v : -1e30f;
                    Sacc[mi][ni][r] = v;
                    mx = fmaxf(mx, v);
                }
                #pragma unroll
                for (int sh = 1; sh < 16; sh <<= 1) mx = fmaxf(mx, __shfl_xor(mx, sh));
                if (lane15 == 0) sRm[rowl * 4 + wk] = mx;
            }
        bar_lgkm();                          // (A): sRm visible

        // ---- part 2 (all threads, no barrier B): m,alpha redundantly; P;
        //      rescale O; per-slice row sums ----
        #pragma unroll
        for (int mi = 0; mi < 2; ++mi)
            #pragma unroll
            for (int r = 0; r < 4; ++r) {
                const int rowl = wq * 32 + mi * 16 + quad * 4 + r;
                const f32x4 pm = *(const f32x4*)&sRm[rowl * 4];   // broadcast b128
                const float m_old = sM[rowl];
                const float mn = fmaxf(fmaxf(fmaxf(pm[0], pm[1]), fmaxf(pm[2], pm[3])), m_old);
                const float al = __expf(m_old - mn);
                mn_[mi][r] = mn; al_[mi][r] = al;
                float sum = 0.f;
                #pragma unroll
                for (int ni = 0; ni < 2; ++ni) {
                    const float p = __expf(Sacc[mi][ni][r] - mn);
                    sP[rowl * 136 + wk * 32 + ni * 16 + lane15] = f2bf(p);
                    sum += p;
                }
                #pragma unroll
                for (int ci = 0; ci < 8; ++ci) Oacc[mi][ci][r] *= al;
                #pragma unroll
                for (int sh = 1; sh < 16; sh <<= 1) sum += __shfl_xor(sum, sh);
                if (lane15 == 0) sRs[rowl * 4 + wk] = sum;
            }
        bar_all();                           // (C): sP + sRs visible, V0 arrived

        // ---- part 3: designated lanes update per-row m/l (no barrier;
        //      consumers are >=1 barrier away) ----
        if (wk == 0 && lane15 == 0) {
            #pragma unroll
            for (int mi = 0; mi < 2; ++mi)
                #pragma unroll
                for (int r = 0; r < 4; ++r) {
                    const int rowl = wq * 32 + mi * 16 + quad * 4 + r;
                    const f32x4 ps = *(const f32x4*)&sRs[rowl * 4];
                    sL[rowl] = sL[rowl] * al_[mi][r] + (ps[0] + ps[1] + ps[2] + ps[3]);
                    sM[rowl] = mn_[mi][r];
                }
        }

        // ---- PV: O(64x512) += P(64x128) . KV(128x512), 4 t-chunks of 32 ----
        #pragma unroll
        for (int tc = 0; tc < 4; ++tc) {
            const int cur = tc & 1;
            if (tc < 3)                 stageV(kt, tc + 1, cur ^ 1);
            else if (kt0 + 1 < ktiles)  stageK(kt + 128, 0, 0);   // next tile's K0
            s16x8 pf[2], vf[8];
            #pragma unroll
            for (int mi = 0; mi < 2; ++mi)
                pf[mi] = *(const s16x8*)&sP[(wq * 32 + mi * 16 + lane15) * 136 + tc * 32 + quad * 8];
            #pragma unroll
            for (int ci = 0; ci < 8; ++ci)
                vf[ci] = *(const s16x8*)&sKV[cur][(wk * 128 + ci * 16 + lane15) * 32 + qx8];
            __builtin_amdgcn_s_setprio(1);
            #pragma unroll
            for (int mi = 0; mi < 2; ++mi)
                #pragma unroll
                for (int ci = 0; ci < 8; ++ci)
                    Oacc[mi][ci] = __builtin_amdgcn_mfma_f32_16x16x32_bf16(pf[mi], vf[ci], Oacc[mi][ci], 0, 0, 0);
            __builtin_amdgcn_s_setprio(0);
            bar_vm();                        // publish V(tc+1) / next K0
        }
    }

    // ---- epilogue: O/l -> bf16, overwrite Qpack[..., 0:512] ----
    bar_lgkm();
    #pragma unroll
    for (int mi = 0; mi < 2; ++mi)
        #pragma unroll
        for (int r = 0; r < 4; ++r) {
            const int rowl = wq * 32 + mi * 16 + quad * 4 + r;
            const float inv = 1.f / sL[rowl];
            #pragma unroll
            for (int ci = 0; ci < 8; ++ci)
                Qrow[(size_t)rowl * 576 + wk * 128 + ci * 16 + lane15] =
                    f2bf(Oacc[mi][ci][r] * inv);
        }
}

// ---------------------------------------------------------------------------
__global__ __launch_bounds__(256)
void cast_f32_bf16(const float* __restrict__ src, u16* __restrict__ dst, int n)
{
    for (int i = blockIdx.x * 256 + threadIdx.x; i < n; i += gridDim.x * 256)
        dst[i] = f2bf(src[i]);
}

__global__ __launch_bounds__(256)
void prep_wbnT(const float* __restrict__ wkvb, u16* __restrict__ dst)
{
    int i = blockIdx.x * 256 + threadIdx.x;
    int h = i >> 16, rem = i & 65535, c = rem >> 7, d = rem & 127;
    dst[i] = f2bf(wkvb[(size_t)(h * 256 + d) * 512 + c]);
}

__global__ __launch_bounds__(256)
void prep_wbv(const float* __restrict__ wkvb, u16* __restrict__ dst)
{
    int i = blockIdx.x * 256 + threadIdx.x;
    int h = i >> 16, rem = i & 65535;
    dst[i] = f2bf(wkvb[(size_t)h * 131072 + 65536 + rem]);
}

__global__ __launch_bounds__(256)
void rmsnorm_bf16(u16* __restrict__ X, const float* __restrict__ w, int D)
{
    const int m = blockIdx.x;
    u16* x = X + (size_t)m * D;
    float ss = 0.f;
    for (int k = threadIdx.x; k < D; k += 256) { float v = bf2f(x[k]); ss += v * v; }
    __shared__ float red[256];
    red[threadIdx.x] = ss; __syncthreads();
    for (int s = 128; s > 0; s >>= 1) {
        if (threadIdx.x < s) red[threadIdx.x] += red[threadIdx.x + s];
        __syncthreads();
    }
    const float sc = rsqrtf(red[0] / (float)D + 1e-6f);
    for (int k = threadIdx.x; k < D; k += 256) x[k] = f2bf(bf2f(x[k]) * sc * w[k]);
}

// q (bf16, rows QSTR) -> rotate q_pe, write to Qpack[h][m][512:576]
__global__ __launch_bounds__(256)
void rope_q(const u16* __restrict__ q, const float* __restrict__ freqs, u16* __restrict__ Qp)
{
    const int idx = blockIdx.x * 256 + threadIdx.x;
    const int i = idx & 31, h = (idx >> 5) & 15, m = idx >> 9;
    const int s = m & (S_ - 1);
    const float c = freqs[(s * 32 + i) * 2], sn = freqs[(s * 32 + i) * 2 + 1];
    const u16* src = q + (size_t)m * QSTR + h * QKH_ + QKN_ + 2 * i;
    const float x0 = bf2f(src[0]), x1 = bf2f(src[1]);
    u16* dst = Qp + ((size_t)h * M_TOT + m) * 576 + 512 + 2 * i;
    dst[0] = f2bf(x0 * c - x1 * sn);
    dst[1] = f2bf(x1 * c + x0 * sn);
}

__global__ __launch_bounds__(256)
void kv_norm_rope(const u16* __restrict__ kva, const float* __restrict__ w,
                  const float* __restrict__ freqs, u16* __restrict__ Kcat)
{
    const int m = blockIdx.x, s = m & (S_ - 1);
    const u16* x = kva + (size_t)m * 576;
    float ss = 0.f;
    for (int k = threadIdx.x; k < 512; k += 256) { float v = bf2f(x[k]); ss += v * v; }
    __shared__ float red[256];
    red[threadIdx.x] = ss; __syncthreads();
    for (int st = 128; st > 0; st >>= 1) {
        if (threadIdx.x < st) red[threadIdx.x] += red[threadIdx.x + st];
        __syncthreads();
    }
    const float sc = rsqrtf(red[0] / 512.f + 1e-6f);
    for (int k = threadIdx.x; k < 512; k += 256)
        Kcat[(size_t)m * 576 + k] = f2bf(bf2f(x[k]) * sc * w[k]);
    if (threadIdx.x < 32) {
        const int i = threadIdx.x;
        const float c = freqs[(s * 32 + i) * 2], sn = freqs[(s * 32 + i) * 2 + 1];
        const float x0 = bf2f(x[512 + 2 * i]), x1 = bf2f(x[512 + 2 * i + 1]);
        Kcat[(size_t)m * 576 + 512 + 2 * i]     = f2bf(x0 * c - x1 * sn);
        Kcat[(size_t)m * 576 + 512 + 2 * i + 1] = f2bf(x1 * c + x0 * sn);
    }
}

__global__ __launch_bounds__(256)
void transpose_kv(const u16* __restrict__ Kcat, u16* __restrict__ KVT)
{
    __shared__ u16 t[64][65];
    const int s0 = blockIdx.x * 64, c0 = blockIdx.y * 64, b = blockIdx.z;
    #pragma unroll
    for (int i = 0; i < 16; ++i) {
        int id = i * 256 + threadIdx.x, r = id >> 6, c = id & 63;
        t[r][c] = Kcat[(size_t)(b * S_ + s0 + r) * 576 + c0 + c];
    }
    __syncthreads();
    #pragma unroll
    for (int i = 0; i < 16; ++i) {
        int id = i * 256 + threadIdx.x, r = id >> 6, c = id & 63;
        KVT[(size_t)(b * 512 + c0 + r) * S_ + s0 + c] = t[c][r];
    }
}

// ---------------------------------------------------------------------------
extern "C" void kernel_launch(void* const* d_in, const int* in_sizes, int n_in,
                              void* d_out, int out_size, void* d_ws, size_t ws_size,
                              hipStream_t stream)
{
    (void)in_sizes; (void)n_in; (void)out_size; (void)ws_size;
    const float* x         = (const float*)d_in[0];
    const float* freqs     = (const float*)d_in[1];
    const float* wq_a_w    = (const float*)d_in[4];
    const float* wq_a_b    = (const float*)d_in[5];
    const float* q_norm_w  = (const float*)d_in[6];
    const float* wq_b_w    = (const float*)d_in[7];
    const float* wq_b_b    = (const float*)d_in[8];
    const float* wkv_a_w   = (const float*)d_in[9];
    const float* wkv_a_b   = (const float*)d_in[10];
    const float* kv_norm_w = (const float*)d_in[11];
    const float* wkv_b_w   = (const float*)d_in[12];
    const float* wo_w      = (const float*)d_in[13];
    const float* wo_b      = (const float*)d_in[14];
    float* out = (float*)d_out;

    char* W = (char*)d_ws;
    u16* x_bf  = (u16*)(W + 0);
    u16* wqa   = (u16*)(W + 16777216);
    u16* wqb   = (u16*)(W + 23068672);
    u16* wkva  = (u16*)(W + 32505856);
    u16* wobf  = (u16*)(W + 34865152);
    u16* wbnT  = (u16*)(W + 43253760);
    u16* wbv   = (u16*)(W + 45350912);
    u16* q_a   = (u16*)(W + 47448064);
    u16* q     = (u16*)(W + 60030976);
    u16* kv_a  = (u16*)(W + 85196800);
    u16* Kcat  = (u16*)(W + 89915392);
    u16* KVT   = (u16*)(W + 94633984);
    u16* Qp    = (u16*)(W + 98828288);   // Qpack[h][4096][576]: q_abs|q_pe -> attn out
    u16* outh  = (u16*)(W + 174325760);

    const dim3 blk(256);

    // --- dtype prep ---
    cast_f32_bf16<<<2048, blk, 0, stream>>>(x, x_bf, M_TOT * DIM_);
    cast_f32_bf16<<<2048, blk, 0, stream>>>(wq_a_w, wqa, QL_ * DIM_);
    cast_f32_bf16<<<2048, blk, 0, stream>>>(wq_b_w, wqb, QSTR * QL_);
    cast_f32_bf16<<<2048, blk, 0, stream>>>(wkv_a_w, wkva, 576 * DIM_);
    cast_f32_bf16<<<2048, blk, 0, stream>>>(wo_w, wobf, DIM_ * DIM_);
    prep_wbnT<<<4096, blk, 0, stream>>>(wkv_b_w, wbnT);
    prep_wbv<<<4096, blk, 0, stream>>>(wkv_b_w, wbv);

    // --- q path ---
    gemm_bf16<<<dim3(12, 32, 1), blk, 0, stream>>>(x_bf, wqa, wq_a_b, q_a,
        M_TOT, QL_, DIM_, DIM_, DIM_, QL_, 0, 0, 0, 1.f, 0);
    rmsnorm_bf16<<<M_TOT, blk, 0, stream>>>(q_a, q_norm_w, QL_);
    gemm_bf16<<<dim3(24, 32, 1), blk, 0, stream>>>(q_a, wqb, wq_b_b, q,
        M_TOT, QSTR, QL_, QL_, QL_, QSTR, 0, 0, 0, 1.f, 0);
    rope_q<<<(M_TOT * NH_ * 32) / 256, blk, 0, stream>>>(q, freqs, Qp);

    // --- kv path ---
    gemm_bf16<<<dim3(5, 32, 1), blk, 0, stream>>>(x_bf, wkva, wkv_a_b, kv_a,
        M_TOT, 576, DIM_, DIM_, DIM_, 576, 0, 0, 0, 1.f, 0);
    kv_norm_rope<<<M_TOT, blk, 0, stream>>>(kv_a, kv_norm_w, freqs, Kcat);
    transpose_kv<<<dim3(32, 8, 2), blk, 0, stream>>>(Kcat, KVT);

    // --- q absorb: Qpack[h][m][0:512] = q_nope @ wkv_b[h,:128,:] ---
    gemm_bf16<<<dim3(4, 32, 16), blk, 0, stream>>>(q, wbnT, nullptr, Qp,
        M_TOT, 512, 128, QSTR, 128, 576, QKH_, 65536, (long long)M_TOT * 576, 1.f, 0);

    // --- fused flash attention v5 (XCD-swizzled 1D grid) ---
    mla_flash<<<dim3(1024, 1, 1), dim3(512), 0, stream>>>(Qp, Kcat, KVT);

    // --- V projection: outh[m][h*128+d] = O[h][m][:] . wbv[h][d][:] ---
    gemm_bf16<<<dim3(1, 32, 16), blk, 0, stream>>>(Qp, wbv, nullptr, outh,
        M_TOT, VH_, 512, 576, 512, DIM_, (long long)M_TOT * 576, 65536, VH_, 1.f, 0);

    // --- output projection (fp32 out) ---
    gemm_bf16<<<dim3(16, 32, 1), blk, 0, stream>>>(outh, wobf, wo_b, out,
        M_TOT, DIM_, DIM_, DIM_, DIM_, DIM_, 0, 0, 0, 1.f, 1);
}